// Round 1
// baseline (1036.880 us; speedup 1.0000x reference)
//
#include <hip/hip_runtime.h>

#define B_ 8
#define L_ 4800
#define H_ 8
#define D_ 64
#define BH_ 64

// ---------------------------------------------------------------------------
// Kernel A (gram): block = (chunk p, batch b) covers ALL 8 heads of a
// contiguous L-chunk.  8 waves, wave w = head w.  Global loads are fully
// contiguous float4 streams; slabs of 8 L-rows double-buffered in LDS via
// register relay (one barrier per slab).  Per-lane 8x8 register tile of the
// 64x64 Gram.  Sum-of-squares accumulated from the prefetch registers.
// ---------------------------------------------------------------------------
__global__ __launch_bounds__(512, 4) void gram_kernel(
    const float* __restrict__ q, const float* __restrict__ k,
    float* __restrict__ Gp, float* __restrict__ qsqp, float* __restrict__ ksqp,
    const int P, const int NS)
{
  const int p = blockIdx.x;
  const int b = blockIdx.y;
  const int t = threadIdx.x;
  const int w = t >> 6;            // head / wave
  const int lane = t & 63;
  const int r0 = (lane >> 3) * 8;  // Gram row tile
  const int c0 = (lane & 7) * 8;   // Gram col tile
  const int to4 = t * 4;

  __shared__ float Ls[2][2][8 * 512];   // [buf][q/k][8 rows x 512 cols] = 64 KB

  const size_t base = ((size_t)b * L_ + (size_t)p * NS * 8) * 512;
  const float* qb = q + base;
  const float* kb = k + base;

  float accG[8][8] = {};
  float sqq0=0.f,sqq1=0.f,sqq2=0.f,sqq3=0.f;
  float sqk0=0.f,sqk1=0.f,sqk2=0.f,sqk3=0.f;

  // prologue: stage slab 0
  {
    float4 a0 = *(const float4*)(qb + to4);
    float4 a1 = *(const float4*)(qb + 2048 + to4);
    float4 b0 = *(const float4*)(kb + to4);
    float4 b1 = *(const float4*)(kb + 2048 + to4);
    sqq0 += a0.x*a0.x; sqq1 += a0.y*a0.y; sqq2 += a0.z*a0.z; sqq3 += a0.w*a0.w;
    sqq0 += a1.x*a1.x; sqq1 += a1.y*a1.y; sqq2 += a1.z*a1.z; sqq3 += a1.w*a1.w;
    sqk0 += b0.x*b0.x; sqk1 += b0.y*b0.y; sqk2 += b0.z*b0.z; sqk3 += b0.w*b0.w;
    sqk0 += b1.x*b1.x; sqk1 += b1.y*b1.y; sqk2 += b1.z*b1.z; sqk3 += b1.w*b1.w;
    *(float4*)&Ls[0][0][to4] = a0;
    *(float4*)&Ls[0][0][2048 + to4] = a1;
    *(float4*)&Ls[0][1][to4] = b0;
    *(float4*)&Ls[0][1][2048 + to4] = b1;
  }
  __syncthreads();

  for (int s = 0; s < NS; s++) {
    const int cur = s & 1;
    float4 a0, a1, b0, b1;
    const bool pf = (s + 1 < NS);
    if (pf) {
      const float* qp = qb + (size_t)(s + 1) * 4096;
      const float* kp = kb + (size_t)(s + 1) * 4096;
      a0 = *(const float4*)(qp + to4);
      a1 = *(const float4*)(qp + 2048 + to4);
      b0 = *(const float4*)(kp + to4);
      b1 = *(const float4*)(kp + 2048 + to4);
    }
    const float* Lq = &Ls[cur][0][w * 64];
    const float* Lk = &Ls[cur][1][w * 64];
#pragma unroll
    for (int r = 0; r < 8; r++) {
      float4 qa0 = *(const float4*)(Lq + r * 512 + r0);
      float4 qa1 = *(const float4*)(Lq + r * 512 + r0 + 4);
      float4 kb0 = *(const float4*)(Lk + r * 512 + c0);
      float4 kb1 = *(const float4*)(Lk + r * 512 + c0 + 4);
      float av[8] = {qa0.x,qa0.y,qa0.z,qa0.w,qa1.x,qa1.y,qa1.z,qa1.w};
      float bv[8] = {kb0.x,kb0.y,kb0.z,kb0.w,kb1.x,kb1.y,kb1.z,kb1.w};
#pragma unroll
      for (int i = 0; i < 8; i++)
#pragma unroll
        for (int j = 0; j < 8; j++)
          accG[i][j] = fmaf(av[i], bv[j], accG[i][j]);
    }
    if (pf) {
      sqq0 += a0.x*a0.x; sqq1 += a0.y*a0.y; sqq2 += a0.z*a0.z; sqq3 += a0.w*a0.w;
      sqq0 += a1.x*a1.x; sqq1 += a1.y*a1.y; sqq2 += a1.z*a1.z; sqq3 += a1.w*a1.w;
      sqk0 += b0.x*b0.x; sqk1 += b0.y*b0.y; sqk2 += b0.z*b0.z; sqk3 += b0.w*b0.w;
      sqk0 += b1.x*b1.x; sqk1 += b1.y*b1.y; sqk2 += b1.z*b1.z; sqk3 += b1.w*b1.w;
      *(float4*)&Ls[cur ^ 1][0][to4] = a0;
      *(float4*)&Ls[cur ^ 1][0][2048 + to4] = a1;
      *(float4*)&Ls[cur ^ 1][1][to4] = b0;
      *(float4*)&Ls[cur ^ 1][1][2048 + to4] = b1;
    }
    __syncthreads();
  }

  // Gram partial: wave w owns head w
  float* gout = Gp + ((size_t)(b * 8 + w) * P + p) * 4096;
#pragma unroll
  for (int i = 0; i < 8; i++) {
    *(float4*)(gout + (r0 + i) * 64 + c0) =
        make_float4(accG[i][0], accG[i][1], accG[i][2], accG[i][3]);
    *(float4*)(gout + (r0 + i) * 64 + c0 + 4) =
        make_float4(accG[i][4], accG[i][5], accG[i][6], accG[i][7]);
  }

  // sum-of-squares partials: thread t covered cols (t%128)*4 .. +4
  float* S = &Ls[0][0][0];
  *(float4*)(S + to4)        = make_float4(sqq0, sqq1, sqq2, sqq3);
  *(float4*)(S + 2048 + to4) = make_float4(sqk0, sqk1, sqk2, sqk3);
  __syncthreads();
  if (t < 256) {
    const int tensor = t >> 7;   // 0 = q, 1 = k
    const int C = t & 127;       // column quad
    const float* Sb = S + tensor * 2048;
    float4 s0 = *(const float4*)(Sb + C * 4);
    float4 s1 = *(const float4*)(Sb + (C + 128) * 4);
    float4 s2 = *(const float4*)(Sb + (C + 256) * 4);
    float4 s3 = *(const float4*)(Sb + (C + 384) * 4);
    float4 r = make_float4(s0.x + s1.x + s2.x + s3.x,
                           s0.y + s1.y + s2.y + s3.y,
                           s0.z + s1.z + s2.z + s3.z,
                           s0.w + s1.w + s2.w + s3.w);
    const int h = C >> 4;
    const int dd = (C & 15) * 4;
    float* dst = tensor ? ksqp : qsqp;
    *(float4*)(dst + ((size_t)(b * 8 + h) * P + p) * 64 + dd) = r;
  }
}

// ---------------------------------------------------------------------------
// Kernel B (reduce): sum the P partial Grams + sq partials at full bandwidth.
// grid (8, 64): 512 blocks x 128 threads, each block owns 512 floats of one bh.
// ---------------------------------------------------------------------------
__global__ __launch_bounds__(128) void reduce_kernel(
    const float* __restrict__ Gp, const float* __restrict__ qsqp,
    const float* __restrict__ ksqp, float* __restrict__ Gt,
    float* __restrict__ qst, float* __restrict__ kst, const int P)
{
  const int j8 = blockIdx.x;
  const int bh = blockIdx.y;
  const int t = threadIdx.x;
  const size_t off = (size_t)j8 * 512 + (size_t)t * 4;
  const float* gp = Gp + (size_t)bh * P * 4096 + off;

  float4 a0 = make_float4(0.f,0.f,0.f,0.f);
  float4 a1 = make_float4(0.f,0.f,0.f,0.f);
  float4 a2 = make_float4(0.f,0.f,0.f,0.f);
  float4 a3 = make_float4(0.f,0.f,0.f,0.f);
  int p = 0;
  for (; p + 4 <= P; p += 4) {
    float4 g0 = *(const float4*)(gp + (size_t)(p + 0) * 4096);
    float4 g1 = *(const float4*)(gp + (size_t)(p + 1) * 4096);
    float4 g2 = *(const float4*)(gp + (size_t)(p + 2) * 4096);
    float4 g3 = *(const float4*)(gp + (size_t)(p + 3) * 4096);
    a0.x += g0.x; a0.y += g0.y; a0.z += g0.z; a0.w += g0.w;
    a1.x += g1.x; a1.y += g1.y; a1.z += g1.z; a1.w += g1.w;
    a2.x += g2.x; a2.y += g2.y; a2.z += g2.z; a2.w += g2.w;
    a3.x += g3.x; a3.y += g3.y; a3.z += g3.z; a3.w += g3.w;
  }
  for (; p < P; p++) {
    float4 g = *(const float4*)(gp + (size_t)p * 4096);
    a0.x += g.x; a0.y += g.y; a0.z += g.z; a0.w += g.w;
  }
  float4 r = make_float4(a0.x + a1.x + a2.x + a3.x,
                         a0.y + a1.y + a2.y + a3.y,
                         a0.z + a1.z + a2.z + a3.z,
                         a0.w + a1.w + a2.w + a3.w);
  *(float4*)(Gt + (size_t)bh * 4096 + off) = r;

  if (j8 == 0) {
    const int d2 = t & 63;
    const float* sp = (t < 64) ? qsqp : ksqp;
    const float* s = sp + (size_t)bh * P * 64 + d2;
    float x0 = 0.f, x1 = 0.f, x2 = 0.f, x3 = 0.f;
    int pp = 0;
    for (; pp + 4 <= P; pp += 4) {
      x0 += s[(size_t)(pp + 0) * 64];
      x1 += s[(size_t)(pp + 1) * 64];
      x2 += s[(size_t)(pp + 2) * 64];
      x3 += s[(size_t)(pp + 3) * 64];
    }
    for (; pp < P; pp++) x0 += s[(size_t)pp * 64];
    float* dst = (t < 64) ? qst : kst;
    dst[bh * 64 + d2] = x0 + x1 + x2 + x3;
  }
}

// ---------------------------------------------------------------------------
// Kernel C (mask): per (b,h) 64x64 postprocessing: normalize, gates,
// temperature, 4x exact top-k (rank counting) + masked softmax -> M.
// Identical logic to the verified version; reads pre-reduced G / sq sums.
// ---------------------------------------------------------------------------
__global__ __launch_bounds__(256) void mask_kernel(
    const float* __restrict__ Gt, const float* __restrict__ qst,
    const float* __restrict__ kst,
    const float* __restrict__ temperature, const float* __restrict__ attns,
    const float* __restrict__ row_w, const float* __restrict__ row_b,
    const float* __restrict__ col_w, const float* __restrict__ col_b,
    float* __restrict__ M)
{
  const int bh = blockIdx.x;
  const int h = bh & 7;
  const int t = threadIdx.x;
  const int d = t & 63, q4 = t >> 6;
  const int e0 = q4 * 16;

  __shared__ float att[64][65];
  __shared__ float rnq[64], rnk[64], cw[64], rw[64];
  __shared__ float wcol[64], wrow[64];
  __shared__ float thr[4][64];
  __shared__ float pmax[4][64];
  __shared__ float rowmax[64];
  __shared__ float psum[4][4][64];
  __shared__ float rinv[4][64];

  if (t < 64) {
    rnq[t] = 1.0f / fmaxf(sqrtf(qst[bh * 64 + t]), 1e-12f);
  } else if (t < 128) {
    rnk[t - 64] = 1.0f / fmaxf(sqrtf(kst[bh * 64 + (t - 64)]), 1e-12f);
  } else if (t < 192) {
    cw[t - 128] = col_w[t - 128];
  } else {
    rw[t - 192] = row_w[t - 192];
  }
  __syncthreads();

  {
    const float rq = rnq[d];
#pragma unroll
    for (int ee = 0; ee < 16; ee += 4) {
      float4 g = *(const float4*)&Gt[(size_t)bh * 4096 + d * 64 + e0 + ee];
      att[d][e0+ee+0] = g.x * rq * rnk[e0+ee+0];
      att[d][e0+ee+1] = g.y * rq * rnk[e0+ee+1];
      att[d][e0+ee+2] = g.z * rq * rnk[e0+ee+2];
      att[d][e0+ee+3] = g.w * rq * rnk[e0+ee+3];
    }
  }
  __syncthreads();

  if (t < 64) {
    float s = 0.f;
    for (int c = 0; c < 64; c++) s += att[c][t] * cw[c];
    s += col_b[0];
    wcol[t] = 1.0f / (1.0f + __expf(-s));
  } else if (t < 128) {
    int c = t - 64;
    float s = 0.f;
    for (int e = 0; e < 64; e++) s += att[c][e] * rw[e];
    s += row_b[0];
    wrow[c] = 1.0f / (1.0f + __expf(-s));
  }
  __syncthreads();

  {
    const float temp = temperature[h];
    const float wr = wrow[d];
    float mx = -1e30f;
#pragma unroll
    for (int ee = 0; ee < 16; ee++) {
      float x = att[d][e0+ee] * ((wcol[e0+ee] + wr) * temp);
      att[d][e0+ee] = x;
      mx = fmaxf(mx, x);
    }
    pmax[q4][d] = mx;
  }
  __syncthreads();
  if (t < 64)
    rowmax[t] = fmaxf(fmaxf(pmax[0][t], pmax[1][t]), fmaxf(pmax[2][t], pmax[3][t]));

  // exact k-th largest by rank counting (tie-exact like lax.top_k)
  {
    float x[16];
#pragma unroll
    for (int j = 0; j < 16; j++) x[j] = att[d][e0+j];
    int gt[16] = {}, ge[16] = {};
    for (int m = 0; m < 64; m++) {
      float y = att[d][m];
#pragma unroll
      for (int j = 0; j < 16; j++) { gt[j] += (y > x[j]); ge[j] += (y >= x[j]); }
    }
    const int tks[4] = {32, 42, 48, 51};
#pragma unroll
    for (int j = 0; j < 16; j++)
#pragma unroll
      for (int i = 0; i < 4; i++)
        if (gt[j] <= tks[i]-1 && ge[j] >= tks[i]) thr[i][d] = x[j];
  }
  __syncthreads();

  {
    const float rm = rowmax[d];
    const float t0 = thr[0][d], t1 = thr[1][d], t2 = thr[2][d], t3 = thr[3][d];
    float s0=0.f, s1=0.f, s2=0.f, s3=0.f;
#pragma unroll
    for (int ee = 0; ee < 16; ee++) {
      float xv = att[d][e0+ee];
      float ex = __expf(xv - rm);
      if (xv >= t0) s0 += ex;
      if (xv >= t1) s1 += ex;
      if (xv >= t2) s2 += ex;
      if (xv >= t3) s3 += ex;
    }
    psum[q4][0][d] = s0; psum[q4][1][d] = s1; psum[q4][2][d] = s2; psum[q4][3][d] = s3;
  }
  __syncthreads();
  if (t < 64) {
#pragma unroll
    for (int i = 0; i < 4; i++) {
      float s = psum[0][i][t] + psum[1][i][t] + psum[2][i][t] + psum[3][i][t];
      rinv[i][t] = attns[i] / s;
    }
  }
  __syncthreads();

  {
    const float rm = rowmax[d];
    const float t0 = thr[0][d], t1 = thr[1][d], t2 = thr[2][d], t3 = thr[3][d];
    const float r0 = rinv[0][d], r1 = rinv[1][d], r2 = rinv[2][d], r3 = rinv[3][d];
    float* mo = M + (size_t)bh * 4096 + d * 64 + e0;
#pragma unroll
    for (int ee = 0; ee < 16; ee++) {
      float xv = att[d][e0+ee];
      float ex = __expf(xv - rm);
      float m = 0.f;
      if (xv >= t0) m += r0 * ex;
      if (xv >= t1) m += r1 * ex;
      if (xv >= t2) m += r2 * ex;
      if (xv >= t3) m += r3 * ex;
      mo[ee] = m;
    }
  }
}

// ---------------------------------------------------------------------------
// Kernel D (apply): out[b,l,h,:] = M_bh * v[b,l,h,:].  No LDS, no barriers:
// lane = one token l, v-row (256 B contiguous) in 64 VGPRs; M rows are
// wave-uniform (scalar loads, SGPR operand in the FMA) -> 1 FMA per output.
// ---------------------------------------------------------------------------
__global__ __launch_bounds__(512, 4) void apply_kernel(
    const float* __restrict__ M, const float* __restrict__ v,
    float* __restrict__ out)
{
  const int lb = blockIdx.x;
  const int b = blockIdx.y;
  const int t = threadIdx.x;
  const int w = __builtin_amdgcn_readfirstlane(t >> 6);   // head (wave-uniform)
  const int lane = t & 63;
  const int l = lb * 64 + lane;

  const float* vrow = v + ((size_t)(b * L_ + l) * 8 + w) * 64;
  float vreg[64];
#pragma unroll
  for (int j = 0; j < 16; j++) {
    float4 x = *(const float4*)(vrow + j * 4);
    vreg[j*4+0] = x.x; vreg[j*4+1] = x.y; vreg[j*4+2] = x.z; vreg[j*4+3] = x.w;
  }

  const float* Mb = M + (size_t)(b * 8 + w) * 4096;
  float* orow = out + ((size_t)(b * L_ + l) * 8 + w) * 64;

  for (int dg = 0; dg < 16; dg++) {
    const float* mr = Mb + dg * 256;    // 4 consecutive M rows (wave-uniform)
    float ob[4];
#pragma unroll
    for (int r = 0; r < 4; r++) {
      float a0 = 0.f, a1 = 0.f;
#pragma unroll
      for (int e = 0; e < 64; e += 2) {
        a0 = fmaf(mr[r * 64 + e],     vreg[e],     a0);
        a1 = fmaf(mr[r * 64 + e + 1], vreg[e + 1], a1);
      }
      ob[r] = a0 + a1;
    }
    *(float4*)(orow + dg * 4) = make_float4(ob[0], ob[1], ob[2], ob[3]);
  }
}

// ---------------------------------------------------------------------------
extern "C" void kernel_launch(void* const* d_in, const int* in_sizes, int n_in,
                              void* d_out, int out_size, void* d_ws, size_t ws_size,
                              hipStream_t stream) {
  const float* q           = (const float*)d_in[0];
  const float* k           = (const float*)d_in[1];
  const float* v           = (const float*)d_in[2];
  const float* temperature = (const float*)d_in[3];
  const float* attns       = (const float*)d_in[4];
  const float* row_w       = (const float*)d_in[5];
  const float* row_b       = (const float*)d_in[6];
  const float* col_w       = (const float*)d_in[7];
  const float* col_b       = (const float*)d_in[8];
  float* out = (float*)d_out;

  // workspace tiering: P = partial Grams per (b,h); need = (270336*P + 532480)*4 B
  auto needB = [](long long P) -> size_t {
    return (size_t)(270336LL * P + 532480LL) * 4u;
  };
  int P = 60;
  if (ws_size < needB(60)) P = 30;
  if (ws_size < needB(30)) P = 15;
  const int NS = 600 / P;          // 8-row slabs per chunk (chunk = NS*8 tokens)

  float* ws = (float*)d_ws;
  const size_t GPs = (size_t)64 * P * 4096;
  const size_t SQs = (size_t)64 * P * 64;
  float* Gp   = ws;
  float* qsqp = Gp + GPs;
  float* ksqp = qsqp + SQs;
  float* Gt   = ksqp + SQs;        // 64*4096
  float* qst  = Gt + 262144;       // 64*64
  float* kst  = qst + 4096;        // 64*64
  float* M    = kst + 4096;        // 64*4096

  gram_kernel<<<dim3(P, B_), 512, 0, stream>>>(q, k, Gp, qsqp, ksqp, P, NS);
  reduce_kernel<<<dim3(8, BH_), 128, 0, stream>>>(Gp, qsqp, ksqp, Gt, qst, kst, P);
  mask_kernel<<<dim3(BH_), 256, 0, stream>>>(Gt, qst, kst, temperature, attns,
                                             row_w, row_b, col_w, col_b, M);
  apply_kernel<<<dim3(L_ / 64, B_), 512, 0, stream>>>(M, v, out);
}

// Round 2
// 339.479 us; speedup vs baseline: 3.0543x; 3.0543x over previous
//
#include <hip/hip_runtime.h>

#define B_ 8
#define L_ 4800
#define H_ 8
#define D_ 64
#define BH_ 64

// ---------------------------------------------------------------------------
// Kernel A (gram): grid (P, B, 2).  Block = 256 thr (4 waves) covers a
// contiguous token chunk (NS*8 rows) for 4 heads (hg selects heads 0-3 or
// 4-7).  Global loads are 1KB-contiguous per wave (cols hg*256..+255 of each
// 2KB row), cooperatively staged into per-head LDS slabs (one barrier/slab,
// double-buffered).  Wave w computes head hg*4+w's full 64x64 partial Gram
// with the round-0-proven 8x8 register outer-product (no launch-bounds reg
// squeeze -> accumulator stays in AGPRs, no spill).
// ---------------------------------------------------------------------------
__global__ __launch_bounds__(256) void gram_kernel(
    const float* __restrict__ q, const float* __restrict__ k,
    float* __restrict__ Gp, float* __restrict__ qsqp, float* __restrict__ ksqp,
    const int P, const int NS)
{
  const int p  = blockIdx.x;
  const int b  = blockIdx.y;
  const int hg = blockIdx.z;            // head group: heads hg*4 .. hg*4+3
  const int t = threadIdx.x;
  const int w = t >> 6, lane = t & 63;
  const int r0 = (lane >> 3) * 8;       // Gram row tile
  const int c0 = (lane & 7) * 8;        // Gram col tile

  __shared__ float Ls[2][2][4][8][64];  // [buf][q/k][head][row][d] = 32 KB

  const int row  = t >> 6;              // slab row 0..3 (and row+4)
  const int col  = lane * 4;            // 0..252 within the 256-float hg span
  const int head = lane >> 4;           // which head's slab this lane feeds
  const int hc   = (t & 15) * 4;        // dim within head

  const float* qb = q + ((size_t)b * L_ + (size_t)p * NS * 8) * 512 + hg * 256;
  const float* kb = k + ((size_t)b * L_ + (size_t)p * NS * 8) * 512 + hg * 256;
  const size_t off0 = (size_t)row * 512 + col;
  const size_t off1 = off0 + 4 * 512;

  float accG[8][8] = {};
  float sqq0=0.f,sqq1=0.f,sqq2=0.f,sqq3=0.f;
  float sqk0=0.f,sqk1=0.f,sqk2=0.f,sqk3=0.f;

  { // stage slab 0
    float4 a0 = *(const float4*)(qb + off0);
    float4 a1 = *(const float4*)(qb + off1);
    float4 b0 = *(const float4*)(kb + off0);
    float4 b1 = *(const float4*)(kb + off1);
    sqq0 += a0.x*a0.x; sqq1 += a0.y*a0.y; sqq2 += a0.z*a0.z; sqq3 += a0.w*a0.w;
    sqq0 += a1.x*a1.x; sqq1 += a1.y*a1.y; sqq2 += a1.z*a1.z; sqq3 += a1.w*a1.w;
    sqk0 += b0.x*b0.x; sqk1 += b0.y*b0.y; sqk2 += b0.z*b0.z; sqk3 += b0.w*b0.w;
    sqk0 += b1.x*b1.x; sqk1 += b1.y*b1.y; sqk2 += b1.z*b1.z; sqk3 += b1.w*b1.w;
    *(float4*)&Ls[0][0][head][row    ][hc] = a0;
    *(float4*)&Ls[0][0][head][row + 4][hc] = a1;
    *(float4*)&Ls[0][1][head][row    ][hc] = b0;
    *(float4*)&Ls[0][1][head][row + 4][hc] = b1;
  }
  __syncthreads();

  for (int s = 0; s < NS; s++) {
    const int cur = s & 1;
    float4 a0, a1, b0, b1;
    const bool pf = (s + 1 < NS);
    if (pf) {                            // issue next-slab loads early
      const float* qp = qb + (size_t)(s + 1) * 4096;
      const float* kp = kb + (size_t)(s + 1) * 4096;
      a0 = *(const float4*)(qp + off0);
      a1 = *(const float4*)(qp + off1);
      b0 = *(const float4*)(kp + off0);
      b1 = *(const float4*)(kp + off1);
    }
    const float (*Lq)[64] = Ls[cur][0][w];
    const float (*Lk)[64] = Ls[cur][1][w];
#pragma unroll
    for (int r = 0; r < 8; r++) {
      float4 qa0 = *(const float4*)&Lq[r][r0];
      float4 qa1 = *(const float4*)&Lq[r][r0 + 4];
      float4 kb0 = *(const float4*)&Lk[r][c0];
      float4 kb1 = *(const float4*)&Lk[r][c0 + 4];
      float av[8] = {qa0.x,qa0.y,qa0.z,qa0.w,qa1.x,qa1.y,qa1.z,qa1.w};
      float bv[8] = {kb0.x,kb0.y,kb0.z,kb0.w,kb1.x,kb1.y,kb1.z,kb1.w};
#pragma unroll
      for (int i = 0; i < 8; i++)
#pragma unroll
        for (int j = 0; j < 8; j++)
          accG[i][j] = fmaf(av[i], bv[j], accG[i][j]);
    }
    if (pf) {
      sqq0 += a0.x*a0.x; sqq1 += a0.y*a0.y; sqq2 += a0.z*a0.z; sqq3 += a0.w*a0.w;
      sqq0 += a1.x*a1.x; sqq1 += a1.y*a1.y; sqq2 += a1.z*a1.z; sqq3 += a1.w*a1.w;
      sqk0 += b0.x*b0.x; sqk1 += b0.y*b0.y; sqk2 += b0.z*b0.z; sqk3 += b0.w*b0.w;
      sqk0 += b1.x*b1.x; sqk1 += b1.y*b1.y; sqk2 += b1.z*b1.z; sqk3 += b1.w*b1.w;
      *(float4*)&Ls[cur ^ 1][0][head][row    ][hc] = a0;
      *(float4*)&Ls[cur ^ 1][0][head][row + 4][hc] = a1;
      *(float4*)&Ls[cur ^ 1][1][head][row    ][hc] = b0;
      *(float4*)&Ls[cur ^ 1][1][head][row + 4][hc] = b1;
    }
    __syncthreads();
  }

  // Gram partial: wave w owns head hg*4+w entirely -> no cross-wave reduction
  float* gout = Gp + ((size_t)(b * 8 + hg * 4 + w) * P + p) * 4096;
#pragma unroll
  for (int i = 0; i < 8; i++) {
    *(float4*)(gout + (r0 + i) * 64 + c0) =
        make_float4(accG[i][0], accG[i][1], accG[i][2], accG[i][3]);
    *(float4*)(gout + (r0 + i) * 64 + c0 + 4) =
        make_float4(accG[i][4], accG[i][5], accG[i][6], accG[i][7]);
  }

  // sum-of-squares partials: thread covered dims (head, hc..hc+3) on rows
  // {row,row+4} of every slab; reduce over the 4 waves via LDS.
  __syncthreads();
  float4* S4 = (float4*)&Ls[0][0][0][0][0];
  S4[t]       = make_float4(sqq0, sqq1, sqq2, sqq3);
  S4[256 + t] = make_float4(sqk0, sqk1, sqk2, sqk3);
  __syncthreads();
  if (t < 128) {
    const int tensor = t >> 6;          // 0 = q, 1 = k
    const int ln = t & 63;
    const float4* Sb = S4 + tensor * 256;
    float4 s0 = Sb[ln], s1 = Sb[64 + ln], s2 = Sb[128 + ln], s3 = Sb[192 + ln];
    float4 r = make_float4(s0.x + s1.x + s2.x + s3.x,
                           s0.y + s1.y + s2.y + s3.y,
                           s0.z + s1.z + s2.z + s3.z,
                           s0.w + s1.w + s2.w + s3.w);
    const int hd = ln >> 4;
    const int dd = (ln & 15) * 4;
    float* dst = tensor ? ksqp : qsqp;
    *(float4*)(dst + ((size_t)(b * 8 + hg * 4 + hd) * P + p) * 64 + dd) = r;
  }
}

// ---------------------------------------------------------------------------
// Kernel B (reduce): sum the P partial Grams + sq partials at full bandwidth.
// grid (8, 64): 512 blocks x 128 threads, each block owns 512 floats of one bh.
// ---------------------------------------------------------------------------
__global__ __launch_bounds__(128) void reduce_kernel(
    const float* __restrict__ Gp, const float* __restrict__ qsqp,
    const float* __restrict__ ksqp, float* __restrict__ Gt,
    float* __restrict__ qst, float* __restrict__ kst, const int P)
{
  const int j8 = blockIdx.x;
  const int bh = blockIdx.y;
  const int t = threadIdx.x;
  const size_t off = (size_t)j8 * 512 + (size_t)t * 4;
  const float* gp = Gp + (size_t)bh * P * 4096 + off;

  float4 a0 = make_float4(0.f,0.f,0.f,0.f);
  float4 a1 = make_float4(0.f,0.f,0.f,0.f);
  float4 a2 = make_float4(0.f,0.f,0.f,0.f);
  float4 a3 = make_float4(0.f,0.f,0.f,0.f);
  int p = 0;
  for (; p + 4 <= P; p += 4) {
    float4 g0 = *(const float4*)(gp + (size_t)(p + 0) * 4096);
    float4 g1 = *(const float4*)(gp + (size_t)(p + 1) * 4096);
    float4 g2 = *(const float4*)(gp + (size_t)(p + 2) * 4096);
    float4 g3 = *(const float4*)(gp + (size_t)(p + 3) * 4096);
    a0.x += g0.x; a0.y += g0.y; a0.z += g0.z; a0.w += g0.w;
    a1.x += g1.x; a1.y += g1.y; a1.z += g1.z; a1.w += g1.w;
    a2.x += g2.x; a2.y += g2.y; a2.z += g2.z; a2.w += g2.w;
    a3.x += g3.x; a3.y += g3.y; a3.z += g3.z; a3.w += g3.w;
  }
  for (; p < P; p++) {
    float4 g = *(const float4*)(gp + (size_t)p * 4096);
    a0.x += g.x; a0.y += g.y; a0.z += g.z; a0.w += g.w;
  }
  float4 r = make_float4(a0.x + a1.x + a2.x + a3.x,
                         a0.y + a1.y + a2.y + a3.y,
                         a0.z + a1.z + a2.z + a3.z,
                         a0.w + a1.w + a2.w + a3.w);
  *(float4*)(Gt + (size_t)bh * 4096 + off) = r;

  if (j8 == 0) {
    const int d2 = t & 63;
    const float* sp = (t < 64) ? qsqp : ksqp;
    const float* s = sp + (size_t)bh * P * 64 + d2;
    float x0 = 0.f, x1 = 0.f, x2 = 0.f, x3 = 0.f;
    int pp = 0;
    for (; pp + 4 <= P; pp += 4) {
      x0 += s[(size_t)(pp + 0) * 64];
      x1 += s[(size_t)(pp + 1) * 64];
      x2 += s[(size_t)(pp + 2) * 64];
      x3 += s[(size_t)(pp + 3) * 64];
    }
    for (; pp < P; pp++) x0 += s[(size_t)pp * 64];
    float* dst = (t < 64) ? qst : kst;
    dst[bh * 64 + d2] = x0 + x1 + x2 + x3;
  }
}

// ---------------------------------------------------------------------------
// Kernel C (mask): per (b,h) 64x64 postprocessing (normalize, gates,
// temperature, 4x exact top-k + masked softmax).  Logic identical to the
// verified version; the combined mask is now stored TRANSPOSED (Mt[e][d])
// for the apply kernel, with coalesced stores (consecutive t -> consecutive d).
// ---------------------------------------------------------------------------
__global__ __launch_bounds__(256) void mask_kernel(
    const float* __restrict__ Gt, const float* __restrict__ qst,
    const float* __restrict__ kst,
    const float* __restrict__ temperature, const float* __restrict__ attns,
    const float* __restrict__ row_w, const float* __restrict__ row_b,
    const float* __restrict__ col_w, const float* __restrict__ col_b,
    float* __restrict__ Mt)
{
  const int bh = blockIdx.x;
  const int h = bh & 7;
  const int t = threadIdx.x;
  const int d = t & 63, q4 = t >> 6;
  const int e0 = q4 * 16;

  __shared__ float att[64][65];
  __shared__ float rnq[64], rnk[64], cw[64], rw[64];
  __shared__ float wcol[64], wrow[64];
  __shared__ float thr[4][64];
  __shared__ float pmax[4][64];
  __shared__ float rowmax[64];
  __shared__ float psum[4][4][64];
  __shared__ float rinv[4][64];

  if (t < 64) {
    rnq[t] = 1.0f / fmaxf(sqrtf(qst[bh * 64 + t]), 1e-12f);
  } else if (t < 128) {
    rnk[t - 64] = 1.0f / fmaxf(sqrtf(kst[bh * 64 + (t - 64)]), 1e-12f);
  } else if (t < 192) {
    cw[t - 128] = col_w[t - 128];
  } else {
    rw[t - 192] = row_w[t - 192];
  }
  __syncthreads();

  {
    const float rq = rnq[d];
#pragma unroll
    for (int ee = 0; ee < 16; ee += 4) {
      float4 g = *(const float4*)&Gt[(size_t)bh * 4096 + d * 64 + e0 + ee];
      att[d][e0+ee+0] = g.x * rq * rnk[e0+ee+0];
      att[d][e0+ee+1] = g.y * rq * rnk[e0+ee+1];
      att[d][e0+ee+2] = g.z * rq * rnk[e0+ee+2];
      att[d][e0+ee+3] = g.w * rq * rnk[e0+ee+3];
    }
  }
  __syncthreads();

  if (t < 64) {
    float s = 0.f;
    for (int c = 0; c < 64; c++) s += att[c][t] * cw[c];
    s += col_b[0];
    wcol[t] = 1.0f / (1.0f + __expf(-s));
  } else if (t < 128) {
    int c = t - 64;
    float s = 0.f;
    for (int e = 0; e < 64; e++) s += att[c][e] * rw[e];
    s += row_b[0];
    wrow[c] = 1.0f / (1.0f + __expf(-s));
  }
  __syncthreads();

  {
    const float temp = temperature[h];
    const float wr = wrow[d];
    float mx = -1e30f;
#pragma unroll
    for (int ee = 0; ee < 16; ee++) {
      float x = att[d][e0+ee] * ((wcol[e0+ee] + wr) * temp);
      att[d][e0+ee] = x;
      mx = fmaxf(mx, x);
    }
    pmax[q4][d] = mx;
  }
  __syncthreads();
  if (t < 64)
    rowmax[t] = fmaxf(fmaxf(pmax[0][t], pmax[1][t]), fmaxf(pmax[2][t], pmax[3][t]));

  // exact k-th largest by rank counting (tie-exact like lax.top_k)
  {
    float x[16];
#pragma unroll
    for (int j = 0; j < 16; j++) x[j] = att[d][e0+j];
    int gt[16] = {}, ge[16] = {};
    for (int m = 0; m < 64; m++) {
      float y = att[d][m];
#pragma unroll
      for (int j = 0; j < 16; j++) { gt[j] += (y > x[j]); ge[j] += (y >= x[j]); }
    }
    const int tks[4] = {32, 42, 48, 51};
#pragma unroll
    for (int j = 0; j < 16; j++)
#pragma unroll
      for (int i = 0; i < 4; i++)
        if (gt[j] <= tks[i]-1 && ge[j] >= tks[i]) thr[i][d] = x[j];
  }
  __syncthreads();

  {
    const float rm = rowmax[d];
    const float t0 = thr[0][d], t1 = thr[1][d], t2 = thr[2][d], t3 = thr[3][d];
    float s0=0.f, s1=0.f, s2=0.f, s3=0.f;
#pragma unroll
    for (int ee = 0; ee < 16; ee++) {
      float xv = att[d][e0+ee];
      float ex = __expf(xv - rm);
      if (xv >= t0) s0 += ex;
      if (xv >= t1) s1 += ex;
      if (xv >= t2) s2 += ex;
      if (xv >= t3) s3 += ex;
    }
    psum[q4][0][d] = s0; psum[q4][1][d] = s1; psum[q4][2][d] = s2; psum[q4][3][d] = s3;
  }
  __syncthreads();
  if (t < 64) {
#pragma unroll
    for (int i = 0; i < 4; i++) {
      float s = psum[0][i][t] + psum[1][i][t] + psum[2][i][t] + psum[3][i][t];
      rinv[i][t] = attns[i] / s;
    }
  }
  __syncthreads();

  {
    const float rm = rowmax[d];
    const float t0 = thr[0][d], t1 = thr[1][d], t2 = thr[2][d], t3 = thr[3][d];
    const float r0 = rinv[0][d], r1 = rinv[1][d], r2 = rinv[2][d], r3 = rinv[3][d];
    float* mo = Mt + (size_t)bh * 4096;
#pragma unroll
    for (int ee = 0; ee < 16; ee++) {
      float xv = att[d][e0+ee];
      float ex = __expf(xv - rm);
      float m = 0.f;
      if (xv >= t0) m += r0 * ex;
      if (xv >= t1) m += r1 * ex;
      if (xv >= t2) m += r2 * ex;
      if (xv >= t3) m += r3 * ex;
      mo[(e0 + ee) * 64 + d] = m;       // transposed, coalesced over d
    }
  }
}

// ---------------------------------------------------------------------------
// Kernel D (apply): out[b,l,h,:] = M_bh * v[b,l,h,:].  One wave per 64-token
// tile; v tile in LDS with XOR bank swizzle (conflict-free ds_read_b128);
// Mt rows read straight from global (1 MB, L2-hot) -> LDS stays at 17 KB,
// 9 blocks/CU.  8x8 register sub-tiles: 256 FMAs per 16 loads.
// ---------------------------------------------------------------------------
__global__ __launch_bounds__(64, 2) void apply_kernel(
    const float* __restrict__ Mt, const float* __restrict__ v,
    float* __restrict__ out)
{
  const int bh = blockIdx.y;
  const int b = bh >> 3, h = bh & 7;
  const int l0 = blockIdx.x * 64;
  const int lane = threadIdx.x;

  __shared__ float Vs[64][68];          // [token][e] with col ^= ((token>>3)<<2)

  // stage v tile: 64 tokens x 64 dims (4 x 256B contiguous segments / instr)
  const int tg  = lane >> 4;
  const int e0w = (lane & 15) * 4;
#pragma unroll
  for (int it = 0; it < 16; it++) {
    const int tl = it * 4 + tg;
    float4 x = *(const float4*)(v + (((size_t)b * L_ + l0 + tl) * 8 + h) * 64 + e0w);
    const int cs = e0w ^ ((tl >> 3) << 2);   // 4-aligned XOR keeps float4 intact
    *(float4*)&Vs[tl][cs] = x;
  }
  __syncthreads();

  const int dg = lane >> 3, lg = lane & 7;
  const int d0 = dg * 8;
  float acc[8][8] = {};                 // [token jj][dim i]
  const float* Mtb = Mt + (size_t)bh * 4096;

  for (int e = 0; e < 64; e += 4) {
    float mt[4][8];
#pragma unroll
    for (int j = 0; j < 4; j++) {
      float4 m0 = *(const float4*)(Mtb + (e + j) * 64 + d0);
      float4 m1 = *(const float4*)(Mtb + (e + j) * 64 + d0 + 4);
      mt[j][0]=m0.x; mt[j][1]=m0.y; mt[j][2]=m0.z; mt[j][3]=m0.w;
      mt[j][4]=m1.x; mt[j][5]=m1.y; mt[j][6]=m1.z; mt[j][7]=m1.w;
    }
#pragma unroll
    for (int jj = 0; jj < 8; jj++) {
      const int tl = lg * 8 + jj;
      const int cs = e ^ (lg << 2);     // tl>>3 == lg
      float4 vv = *(const float4*)&Vs[tl][cs];
#pragma unroll
      for (int i = 0; i < 8; i++) {
        acc[jj][i] = fmaf(mt[0][i], vv.x, acc[jj][i]);
        acc[jj][i] = fmaf(mt[1][i], vv.y, acc[jj][i]);
        acc[jj][i] = fmaf(mt[2][i], vv.z, acc[jj][i]);
        acc[jj][i] = fmaf(mt[3][i], vv.w, acc[jj][i]);
      }
    }
  }

#pragma unroll
  for (int jj = 0; jj < 8; jj++) {
    const int tl = lg * 8 + jj;
    float* orow = out + (((size_t)b * L_ + l0 + tl) * 8 + h) * 64 + d0;
    *(float4*)(orow)     = make_float4(acc[jj][0], acc[jj][1], acc[jj][2], acc[jj][3]);
    *(float4*)(orow + 4) = make_float4(acc[jj][4], acc[jj][5], acc[jj][6], acc[jj][7]);
  }
}

// ---------------------------------------------------------------------------
extern "C" void kernel_launch(void* const* d_in, const int* in_sizes, int n_in,
                              void* d_out, int out_size, void* d_ws, size_t ws_size,
                              hipStream_t stream) {
  const float* q           = (const float*)d_in[0];
  const float* k           = (const float*)d_in[1];
  const float* v           = (const float*)d_in[2];
  const float* temperature = (const float*)d_in[3];
  const float* attns       = (const float*)d_in[4];
  const float* row_w       = (const float*)d_in[5];
  const float* row_b       = (const float*)d_in[6];
  const float* col_w       = (const float*)d_in[7];
  const float* col_b       = (const float*)d_in[8];
  float* out = (float*)d_out;

  // workspace tiering: P = chunks (partials) per (b,h)
  auto needB = [](long long P) -> size_t {
    return (size_t)(270336LL * P + 532480LL) * 4u;
  };
  int P = 60;
  if (ws_size < needB(60)) P = 30;
  if (ws_size < needB(30)) P = 15;
  const int NS = 600 / P;          // 8-row slabs per chunk

  float* ws = (float*)d_ws;
  const size_t GPs = (size_t)64 * P * 4096;
  const size_t SQs = (size_t)64 * P * 64;
  float* Gp   = ws;
  float* qsqp = Gp + GPs;
  float* ksqp = qsqp + SQs;
  float* Gt   = ksqp + SQs;        // 64*4096
  float* qst  = Gt + 262144;       // 64*64
  float* kst  = qst + 4096;        // 64*64
  float* Mt   = kst + 4096;        // 64*4096 (transposed mask)

  gram_kernel<<<dim3(P, B_, 2), 256, 0, stream>>>(q, k, Gp, qsqp, ksqp, P, NS);
  reduce_kernel<<<dim3(8, BH_), 128, 0, stream>>>(Gp, qsqp, ksqp, Gt, qst, kst, P);
  mask_kernel<<<dim3(BH_), 256, 0, stream>>>(Gt, qst, kst, temperature, attns,
                                             row_w, row_b, col_w, col_b, Mt);
  apply_kernel<<<dim3(L_ / 64, BH_), 64, 0, stream>>>(Mt, v, out);
}